// Round 4
// baseline (230.056 us; speedup 1.0000x reference)
//
#include <hip/hip_runtime.h>

#define N_ATOMS 4096
#define D_DESC 352
#define NBLK 512   // max 8-atom blocks per type
typedef unsigned long long ull;

__device__ __forceinline__ float wrap1(float d, float box) {
    return d - box * rintf(d / box);
}

// transposed descriptor/activation layout: [type][blk][feature][q], q = p&7
__device__ __forceinline__ size_t dt_idx(int t, int p, int dd) {
    return (((size_t)t * NBLK + (p >> 3)) * D_DESC + dd) * 8 + (p & 7);
}

__global__ __launch_bounds__(256) void build_lists_kernel(
    const int* __restrict__ types, int* __restrict__ cnt,
    int* __restrict__ lists, int* __restrict__ pos)
{
    int i = blockIdx.x * 256 + threadIdx.x;
    if (i < N_ATOMS) {
        int t = types[i];
        int p = atomicAdd(&cnt[t], 1);
        lists[t * N_ATOMS + p] = i;
        pos[i] = p;
    }
}

// One block per (atom, type). Threshold-filter to <=512 candidates, then
// exact bitonic sort by 43-bit key (d2bits<<12 | j) -> sorted top-128.
__global__ __launch_bounds__(256) void select_kernel(
    const float* __restrict__ xyz, const float* __restrict__ box,
    const int* __restrict__ cnt, const int* __restrict__ lists,
    const int* __restrict__ types, const int* __restrict__ pos,
    float* __restrict__ descT, float* __restrict__ aX, float* __restrict__ aD,
    float* __restrict__ lfD, int* __restrict__ lfJ)
{
    __shared__ int part[2][4];
    __shared__ ull cand[512];
    __shared__ int cpos;

    const int i   = blockIdx.x >> 1;
    const int t   = blockIdx.x & 1;
    const int tid = threadIdx.x;
    const int n   = cnt[t];
    const int nc  = (n + 255) >> 8;
    const float bx = box[0], by = box[1], bz = box[2];
    const float xi = xyz[3*i+0], yi = xyz[3*i+1], zi = xyz[3*i+2];

    float d2r[16];
    #pragma unroll
    for (int c = 0; c < 16; ++c) {
        d2r[c] = __builtin_inff();
        if (c < nc) {
            int m = tid + (c << 8);
            if (m < n) {
                int j = lists[t * N_ATOMS + m];
                if (j != i) {
                    float dx = wrap1(xi - xyz[3*j+0], bx);
                    float dy = wrap1(yi - xyz[3*j+1], by);
                    float dz = wrap1(zi - xyz[3*j+2], bz);
                    d2r[c] = dx*dx + dy*dy + dz*dz;
                }
            }
        }
    }

    if (tid == 0) cpos = 0;

    float T = __powf(45.84f * bx * by * bz / (float)n, 2.0f / 3.0f);
    int tot = 0;
    for (int it = 0; it < 20; ++it) {
        int lc = 0;
        #pragma unroll
        for (int c = 0; c < 16; ++c)
            if (c < nc) lc += (d2r[c] < T) ? 1 : 0;
        #pragma unroll
        for (int off = 32; off > 0; off >>= 1) lc += __shfl_xor(lc, off);
        if ((tid & 63) == 0) part[it & 1][tid >> 6] = lc;
        __syncthreads();
        tot = part[it & 1][0] + part[it & 1][1] + part[it & 1][2] + part[it & 1][3];
        if (tot >= 128 && tot <= 384) break;
        T *= (tot < 128) ? 1.6f : 0.6f;
    }

    #pragma unroll
    for (int c = 0; c < 16; ++c) {
        if (c < nc && d2r[c] < T) {
            int m = tid + (c << 8);
            int j = lists[t * N_ATOMS + m];
            ull key = ((ull)__float_as_uint(d2r[c]) << 12) | (unsigned)j;
            int p = atomicAdd(&cpos, 1);
            if (p < 512) cand[p] = key;
        }
    }
    const int count  = (tot <= 512) ? tot : 512;
    const int sort_n = (count <= 256) ? 256 : 512;
    for (int m = tid + count; m < sort_n; m += 256) cand[m] = ~0ull;
    __syncthreads();

    for (int kk = 2; kk <= sort_n; kk <<= 1) {
        for (int jj = kk >> 1; jj > 0; jj >>= 1) {
            for (int m = tid; m < sort_n; m += 256) {
                int p = m ^ jj;
                if (p > m) {
                    ull a = cand[m], b = cand[p];
                    bool asc = ((m & kk) == 0);
                    if (asc ? (a > b) : (a < b)) { cand[m] = b; cand[p] = a; }
                }
            }
            __syncthreads();
        }
    }

    if (tid < 128) {
        const int ti = types[i];
        const int pi = pos[i];
        ull key = cand[tid];
        int j   = (int)(key & 0xFFF);
        float d2 = __uint_as_float((unsigned)(key >> 12));
        float dist = sqrtf(d2);
        descT[dt_idx(ti, pi, t * 128 + tid)] = 1.0f / (dist + 1e-16f);
        if (tid < 16) {
            float dx = wrap1(xi - xyz[3*j+0], bx);
            float dy = wrap1(yi - xyz[3*j+1], by);
            float dz = wrap1(zi - xyz[3*j+2], bz);
            int s = i * 32 + t * 16 + tid;
            aX[3*s+0] = dx; aX[3*s+1] = dy; aX[3*s+2] = dz;
            aD[s] = dist;
        }
        if (tid < 2) {
            lfD[i * 4 + t * 2 + tid] = dist;
            lfJ[i * 4 + t * 2 + tid] = j;
        }
    }
}

// One block (64 threads) per atom: local frame + rotated angular features.
__global__ __launch_bounds__(64) void finalize_kernel(
    const float* __restrict__ xyz, const float* __restrict__ box,
    const int* __restrict__ types, const int* __restrict__ pos,
    const float* __restrict__ aX, const float* __restrict__ aD,
    const float* __restrict__ lfD, const int* __restrict__ lfJ,
    float* __restrict__ descT)
{
    __shared__ float Amat[9];
    const int i   = blockIdx.x;
    const int tid = threadIdx.x;

    if (tid == 0) {
        const float bx = box[0], by = box[1], bz = box[2];
        const float xi = xyz[3*i+0], yi = xyz[3*i+1], zi = xyz[3*i+2];
        float cd[4]; int cj[4];
        #pragma unroll
        for (int c = 0; c < 4; ++c) { cd[c] = lfD[i*4+c]; cj[c] = lfJ[i*4+c]; }
        int i0 = 0; float b0 = cd[0];
        for (int c = 1; c < 4; ++c) if (cd[c] < b0) { b0 = cd[c]; i0 = c; }
        int i1 = -1; float b1v = 3.4e38f;
        for (int c = 0; c < 4; ++c) { if (c == i0) continue; if (cd[c] < b1v) { b1v = cd[c]; i1 = c; } }

        int ja = cj[i0], jb = cj[i1];
        float da = cd[i0], db = cd[i1];
        float r0x = wrap1(xi - xyz[3*ja+0], bx) / (da + 1e-16f);
        float r0y = wrap1(yi - xyz[3*ja+1], by) / (da + 1e-16f);
        float r0z = wrap1(zi - xyz[3*ja+2], bz) / (da + 1e-16f);
        float r1x = wrap1(xi - xyz[3*jb+0], bx) / (db + 1e-16f);
        float r1y = wrap1(yi - xyz[3*jb+1], by) / (db + 1e-16f);
        float r1z = wrap1(zi - xyz[3*jb+2], bz) / (db + 1e-16f);
        float dot = r0x*r1x + r0y*r1y + r0z*r1z;
        float v2x = r1x - dot*r0x, v2y = r1y - dot*r0y, v2z = r1z - dot*r0z;
        float n2 = sqrtf(v2x*v2x + v2y*v2y + v2z*v2z);
        v2x /= n2; v2y /= n2; v2z /= n2;
        float v3x = r0y*r1z - r0z*r1y;
        float v3y = r0z*r1x - r0x*r1z;
        float v3z = r0x*r1y - r0y*r1x;
        float n3 = sqrtf(v3x*v3x + v3y*v3y + v3z*v3z);
        v3x /= n3; v3y /= n3; v3z /= n3;
        Amat[0]=r0x; Amat[1]=r0y; Amat[2]=r0z;
        Amat[3]=v2x; Amat[4]=v2y; Amat[5]=v2z;
        Amat[6]=v3x; Amat[7]=v3y; Amat[8]=v3z;
    }
    __syncthreads();

    if (tid < 32) {
        const int ti = types[i];
        const int pi = pos[i];
        int s = i * 32 + tid;
        float d  = aD[s];
        float dn = d + 1e-16f;
        float ax = aX[3*s+0] / dn;
        float ay = aX[3*s+1] / dn;
        float az = aX[3*s+2] / dn;
        float o0 = (Amat[0]*ax + Amat[1]*ay + Amat[2]*az) / dn;
        float o1 = (Amat[3]*ax + Amat[4]*ay + Amat[5]*az) / dn;
        float o2 = (Amat[6]*ax + Amat[7]*ay + Amat[8]*az) / dn;
        descT[dt_idx(ti, pi, 256 + 3*tid + 0)] = o0;
        descT[dt_idx(ti, pi, 256 + 3*tid + 1)] = o1;
        descT[dt_idx(ti, pi, 256 + 3*tid + 2)] = o2;
    }
}

// One layer: block = (type, 8-atom blk), thread = output neuron.
// Activations via wave-uniform (scalar-pipe) loads; weights coalesced.
template<int K>
__global__ __launch_bounds__(256) void layer_kernel(
    const int* __restrict__ cnt,
    const float* __restrict__ actT,   // [2][NBLK][K][8]
    const float* __restrict__ W,      // [2][K][256]
    const float* __restrict__ B,      // [2][256]
    float* __restrict__ outT)         // [2][NBLK][256][8]
{
    const int t   = blockIdx.y;
    const int blk = blockIdx.x;
    const int o   = threadIdx.x;
    if (blk * 8 >= cnt[t]) return;

    const float* a = actT + ((size_t)t * NBLK + blk) * ((size_t)K * 8);
    const float* w = W + (size_t)t * K * 256 + o;

    float acc[8];
    const float bias = B[t * 256 + o];
    #pragma unroll
    for (int q = 0; q < 8; ++q) acc[q] = bias;

    #pragma unroll 4
    for (int d = 0; d < K; ++d) {
        float wv = w[(size_t)d * 256];
        const float4* a4 = (const float4*)(a + (size_t)d * 8);
        float4 a0 = a4[0], a1 = a4[1];
        acc[0] = fmaf(a0.x, wv, acc[0]);
        acc[1] = fmaf(a0.y, wv, acc[1]);
        acc[2] = fmaf(a0.z, wv, acc[2]);
        acc[3] = fmaf(a0.w, wv, acc[3]);
        acc[4] = fmaf(a1.x, wv, acc[4]);
        acc[5] = fmaf(a1.y, wv, acc[5]);
        acc[6] = fmaf(a1.z, wv, acc[6]);
        acc[7] = fmaf(a1.w, wv, acc[7]);
    }

    float* op = outT + (((size_t)t * NBLK + blk) * 256 + o) * 8;
    #pragma unroll
    for (int q = 0; q < 8; ++q) op[q] = tanhf(acc[q]);
}

__global__ __launch_bounds__(256) void energy_kernel(
    const int* __restrict__ cnt, const float* __restrict__ h3T,
    const float* __restrict__ w4, const float* __restrict__ b4,
    float* __restrict__ out)
{
    __shared__ float red[256];
    const int t   = blockIdx.y;
    const int blk = blockIdx.x;
    const int o   = threadIdx.x;
    const int n   = cnt[t];
    if (blk * 8 >= n) return;
    const int nv = min(8, n - blk * 8);

    const float* h = h3T + (((size_t)t * NBLK + blk) * 256 + o) * 8;
    float s = 0.0f;
    for (int q = 0; q < nv; ++q) s += h[q];
    red[o] = s * w4[t * 256 + o];
    __syncthreads();
    for (int w = 128; w > 0; w >>= 1) {
        if (o < w) red[o] += red[o + w];
        __syncthreads();
    }
    if (o == 0) atomicAdd(out, red[0] + (float)nv * b4[t]);
}

extern "C" void kernel_launch(void* const* d_in, const int* in_sizes, int n_in,
                              void* d_out, int out_size, void* d_ws, size_t ws_size,
                              hipStream_t stream) {
    const float* xyz   = (const float*)d_in[0];
    const float* box   = (const float*)d_in[1];
    const int*   types = (const int*)  d_in[2];
    const float* w1 = (const float*)d_in[3];
    const float* b1 = (const float*)d_in[4];
    const float* w2 = (const float*)d_in[5];
    const float* b2 = (const float*)d_in[6];
    const float* w3 = (const float*)d_in[7];
    const float* b3 = (const float*)d_in[8];
    const float* w4 = (const float*)d_in[9];
    const float* b4 = (const float*)d_in[10];
    float* out = (float*)d_out;

    // workspace layout (4B units)
    float* p = (float*)d_ws;
    int*   cnt   = (int*)p;            p += 16;
    int*   pos   = (int*)p;            p += N_ATOMS;
    int*   lists = (int*)p;            p += 2 * N_ATOMS;
    float* lfD   = p;                  p += 4 * N_ATOMS;
    int*   lfJ   = (int*)p;            p += 4 * N_ATOMS;
    float* aX    = p;                  p += 96 * N_ATOMS;
    float* aD    = p;                  p += 32 * N_ATOMS;
    float* descT = p;                  p += (size_t)2 * NBLK * D_DESC * 8;
    float* h1T   = p;                  p += (size_t)2 * NBLK * 256 * 8;
    float* h2T   = p;                  p += (size_t)2 * NBLK * 256 * 8;

    hipMemsetAsync(d_out, 0, sizeof(float), stream);
    hipMemsetAsync(d_ws, 0, 2 * sizeof(int), stream);

    build_lists_kernel<<<N_ATOMS / 256, 256, 0, stream>>>(types, cnt, lists, pos);
    select_kernel<<<2 * N_ATOMS, 256, 0, stream>>>(xyz, box, cnt, lists, types, pos,
                                                   descT, aX, aD, lfD, lfJ);
    finalize_kernel<<<N_ATOMS, 64, 0, stream>>>(xyz, box, types, pos,
                                                aX, aD, lfD, lfJ, descT);
    dim3 g(NBLK, 2);
    layer_kernel<D_DESC><<<g, 256, 0, stream>>>(cnt, descT, w1, b1, h1T);
    layer_kernel<256><<<g, 256, 0, stream>>>(cnt, h1T, w2, b2, h2T);
    layer_kernel<256><<<g, 256, 0, stream>>>(cnt, h2T, w3, b3, h1T);
    energy_kernel<<<g, 256, 0, stream>>>(cnt, h1T, w4, b4, out);
}